// Round 1
// baseline (305.837 us; speedup 1.0000x reference)
//
#include <hip/hip_runtime.h>
#include <stdint.h>

#define N_ 8192
#define D_ 1024
#define SCALE 10.0f  // 1 / TEMPERATURE

typedef float f32x4 __attribute__((ext_vector_type(4)));
typedef __bf16 bf16x8 __attribute__((ext_vector_type(8)));

// round-to-nearest-even f32 -> bf16 (inputs are finite; no NaN path needed)
__device__ __forceinline__ unsigned short f2bf(float x) {
  unsigned int u = __float_as_uint(x);
  u += 0x7fffu + ((u >> 16) & 1u);
  return (unsigned short)(u >> 16);
}

__device__ __forceinline__ void load_lds16(const void* g, void* lds) {
  __builtin_amdgcn_global_load_lds(
      (const __attribute__((address_space(1))) unsigned int*)g,
      (__attribute__((address_space(3))) unsigned int*)lds, 16, 0, 0);
}

// Kernel 1: per-row L2 norms, fp32 diag = dot(imn_i, capn_i)*SCALE, bf16 normalized copies.
__global__ __launch_bounds__(256) void normalize_k(
    const float* __restrict__ im, const float* __restrict__ cap,
    unsigned short* __restrict__ imn, unsigned short* __restrict__ capn,
    float* __restrict__ diag) {
  const int row = blockIdx.x;
  const int t = threadIdx.x;
  const float4 a = ((const float4*)(im + (size_t)row * D_))[t];
  const float4 b = ((const float4*)(cap + (size_t)row * D_))[t];
  float ssa = a.x * a.x + a.y * a.y + a.z * a.z + a.w * a.w;
  float ssb = b.x * b.x + b.y * b.y + b.z * b.z + b.w * b.w;
  float dt  = a.x * b.x + a.y * b.y + a.z * b.z + a.w * b.w;
#pragma unroll
  for (int o = 32; o > 0; o >>= 1) {
    ssa += __shfl_down(ssa, o, 64);
    ssb += __shfl_down(ssb, o, 64);
    dt  += __shfl_down(dt, o, 64);
  }
  __shared__ float red[3][4];
  const int w = t >> 6, l = t & 63;
  if (l == 0) { red[0][w] = ssa; red[1][w] = ssb; red[2][w] = dt; }
  __syncthreads();
  ssa = red[0][0] + red[0][1] + red[0][2] + red[0][3];
  ssb = red[1][0] + red[1][1] + red[1][2] + red[1][3];
  dt  = red[2][0] + red[2][1] + red[2][2] + red[2][3];
  const float ra = rsqrtf(ssa), rb = rsqrtf(ssb);
  if (t == 0) diag[row] = dt * ra * rb * SCALE;
  ushort4 pa, pb;
  pa.x = f2bf(a.x * ra); pa.y = f2bf(a.y * ra);
  pa.z = f2bf(a.z * ra); pa.w = f2bf(a.w * ra);
  pb.x = f2bf(b.x * rb); pb.y = f2bf(b.y * rb);
  pb.z = f2bf(b.z * rb); pb.w = f2bf(b.w * rb);
  ((ushort4*)(imn + (size_t)row * D_))[t] = pa;
  ((ushort4*)(capn + (size_t)row * D_))[t] = pb;
}

// Kernel 2: fused tile GEMM + exp + row/col partial sums.
// 128x128 tile per 256-thread block (4 waves, each a 64x64 quadrant of 4x4 MFMA tiles).
__global__ __launch_bounds__(256) void gemm_lse_k(
    const unsigned short* __restrict__ A,   // imn bf16 [N, D]
    const unsigned short* __restrict__ B,   // capn bf16 [N, D]
    float* __restrict__ rowsum, float* __restrict__ colsum) {
  __shared__ __align__(16) unsigned short As[128 * 32];
  __shared__ __align__(16) unsigned short Bs[128 * 32];
  const int t = threadIdx.x;
  const int w = t >> 6, l = t & 63;
  const int rowBase = blockIdx.y * 128;
  const int colBase = blockIdx.x * 128;
  const int wq_m = (w >> 1) * 64, wq_n = (w & 1) * 64;

  f32x4 acc[4][4];
#pragma unroll
  for (int i = 0; i < 4; ++i)
#pragma unroll
    for (int j = 0; j < 4; ++j)
      acc[i][j] = (f32x4){0.f, 0.f, 0.f, 0.f};

  // staging: each thread DMAs one 16B chunk per 64-row round; LDS dest is
  // wave-uniform base + lane*16 (HW constraint) -> row-major [row][k], no pad.
  const int srow = w * 16 + (l >> 2);     // row within the 64-row round
  const int scol = (l & 3) * 8;           // bf16 element offset (16B chunk)
  const size_t gA0 = (size_t)(rowBase + srow) * D_ + scol;
  const size_t gB0 = (size_t)(colBase + srow) * D_ + scol;
  char* ldsA = (char*)As + w * 1024;
  char* ldsB = (char*)Bs + w * 1024;
  const int m15 = l & 15;
  const int kg = (l >> 4) * 8;            // k-group start for A/B fragments

  for (int k0 = 0; k0 < D_; k0 += 32) {
    load_lds16(A + gA0 + k0, ldsA);
    load_lds16(A + gA0 + (size_t)64 * D_ + k0, ldsA + 4096);
    load_lds16(B + gB0 + k0, ldsB);
    load_lds16(B + gB0 + (size_t)64 * D_ + k0, ldsB + 4096);
    __syncthreads();  // drains vmcnt(0): global_load_lds complete

    bf16x8 af[4], bfr[4];
#pragma unroll
    for (int i = 0; i < 4; ++i) {
      af[i]  = *(const bf16x8*)(As + (wq_m + i * 16 + m15) * 32 + kg);
      bfr[i] = *(const bf16x8*)(Bs + (wq_n + i * 16 + m15) * 32 + kg);
    }
#pragma unroll
    for (int mt = 0; mt < 4; ++mt)
#pragma unroll
      for (int nt = 0; nt < 4; ++nt)
        acc[mt][nt] = __builtin_amdgcn_mfma_f32_16x16x32_bf16(
            af[mt], bfr[nt], acc[mt][nt], 0, 0, 0);
    __syncthreads();  // protect LDS before next stage
  }

  // epilogue: exp (fixed-max LSE; logits bounded by +/-10 so no overflow)
#pragma unroll
  for (int mt = 0; mt < 4; ++mt)
#pragma unroll
    for (int nt = 0; nt < 4; ++nt)
#pragma unroll
      for (int r = 0; r < 4; ++r)
        acc[mt][nt][r] = __expf(acc[mt][nt][r] * SCALE);

  // C/D layout: col = lane&15, row = (lane>>4)*4 + reg  [measured m89/m91]
  // row partial sums: reduce across the 16 cols (low 4 lane bits)
#pragma unroll
  for (int mt = 0; mt < 4; ++mt)
#pragma unroll
    for (int r = 0; r < 4; ++r) {
      float v = acc[mt][0][r] + acc[mt][1][r] + acc[mt][2][r] + acc[mt][3][r];
      v += __shfl_xor(v, 1, 64);
      v += __shfl_xor(v, 2, 64);
      v += __shfl_xor(v, 4, 64);
      v += __shfl_xor(v, 8, 64);
      if ((l & 15) == 0)
        atomicAdd(&rowsum[rowBase + wq_m + mt * 16 + (l >> 4) * 4 + r], v);
    }
  // col partial sums: reduce across rows (lane groups, bits 4-5)
#pragma unroll
  for (int nt = 0; nt < 4; ++nt) {
    float v = 0.f;
#pragma unroll
    for (int mt = 0; mt < 4; ++mt)
      v += acc[mt][nt][0] + acc[mt][nt][1] + acc[mt][nt][2] + acc[mt][nt][3];
    v += __shfl_xor(v, 16, 64);
    v += __shfl_xor(v, 32, 64);
    if (l < 16)
      atomicAdd(&colsum[colBase + wq_n + nt * 16 + l], v);
  }
}

// Kernel 3: scalar reduce.
__global__ __launch_bounds__(256) void finalize_k(
    const float* __restrict__ rowsum, const float* __restrict__ colsum,
    const float* __restrict__ diag, float* __restrict__ out) {
  const int t = threadIdx.x;
  float lse = 0.f, dg = 0.f;
  for (int i = t; i < N_; i += 256) {
    lse += __logf(rowsum[i]) + __logf(colsum[i]);
    dg += diag[i];
  }
#pragma unroll
  for (int o = 32; o > 0; o >>= 1) {
    lse += __shfl_down(lse, o, 64);
    dg  += __shfl_down(dg, o, 64);
  }
  __shared__ float red[2][4];
  const int w = t >> 6, l = t & 63;
  if (l == 0) { red[0][w] = lse; red[1][w] = dg; }
  __syncthreads();
  if (t == 0) {
    lse = red[0][0] + red[0][1] + red[0][2] + red[0][3];
    dg  = red[1][0] + red[1][1] + red[1][2] + red[1][3];
    out[0] = 0.5f * lse / (float)N_ - dg / (float)N_;
  }
}

extern "C" void kernel_launch(void* const* d_in, const int* in_sizes, int n_in,
                              void* d_out, int out_size, void* d_ws, size_t ws_size,
                              hipStream_t stream) {
  const float* im = (const float*)d_in[0];
  const float* cap = (const float*)d_in[1];
  float* out = (float*)d_out;
  char* ws = (char*)d_ws;
  unsigned short* imn = (unsigned short*)ws;                       // 16 MB
  unsigned short* capn = imn + (size_t)N_ * D_;                    // 16 MB
  float* rowsum = (float*)(ws + 2 * (size_t)N_ * D_ * sizeof(unsigned short));
  float* colsum = rowsum + N_;
  float* diag = colsum + N_;

  hipMemsetAsync(rowsum, 0, 2 * N_ * sizeof(float), stream);  // rowsum+colsum
  normalize_k<<<N_, 256, 0, stream>>>(im, cap, imn, capn, diag);
  gemm_lse_k<<<dim3(N_ / 128, N_ / 128), 256, 0, stream>>>(imn, capn, rowsum, colsum);
  finalize_k<<<1, 256, 0, stream>>>(rowsum, colsum, diag, out);
}

// Round 2
// 305.101 us; speedup vs baseline: 1.0024x; 1.0024x over previous
//
#include <hip/hip_runtime.h>
#include <stdint.h>

#define N_ 8192
#define D_ 1024
// logit = dot(imn,capn)/T; fp8 operands pre-scaled by 16 -> acc = 256*dot
#define EPILOGUE_SCALE (10.0f / 256.0f)
#define ENC_SCALE 16.0f

typedef float f32x4 __attribute__((ext_vector_type(4)));

__device__ __forceinline__ void load_lds16(const void* g, void* lds) {
  __builtin_amdgcn_global_load_lds(
      (const __attribute__((address_space(1))) unsigned int*)g,
      (__attribute__((address_space(3))) unsigned int*)lds, 16, 0, 0);
}

// Kernel 1: per-row L2 norms, fp32 diag = dot(imn_i, capn_i)*10, fp8(e4m3) normalized copies scaled x16.
__global__ __launch_bounds__(256) void normalize_k(
    const float* __restrict__ im, const float* __restrict__ cap,
    unsigned int* __restrict__ imn, unsigned int* __restrict__ capn,
    float* __restrict__ diag) {
  const int row = blockIdx.x;
  const int t = threadIdx.x;
  const float4 a = ((const float4*)(im + (size_t)row * D_))[t];
  const float4 b = ((const float4*)(cap + (size_t)row * D_))[t];
  float ssa = a.x * a.x + a.y * a.y + a.z * a.z + a.w * a.w;
  float ssb = b.x * b.x + b.y * b.y + b.z * b.z + b.w * b.w;
  float dt  = a.x * b.x + a.y * b.y + a.z * b.z + a.w * b.w;
#pragma unroll
  for (int o = 32; o > 0; o >>= 1) {
    ssa += __shfl_down(ssa, o, 64);
    ssb += __shfl_down(ssb, o, 64);
    dt  += __shfl_down(dt, o, 64);
  }
  __shared__ float red[3][4];
  const int w = t >> 6, l = t & 63;
  if (l == 0) { red[0][w] = ssa; red[1][w] = ssb; red[2][w] = dt; }
  __syncthreads();
  ssa = red[0][0] + red[0][1] + red[0][2] + red[0][3];
  ssb = red[1][0] + red[1][1] + red[1][2] + red[1][3];
  dt  = red[2][0] + red[2][1] + red[2][2] + red[2][3];
  const float ra = rsqrtf(ssa), rb = rsqrtf(ssb);
  if (t == 0) diag[row] = dt * ra * rb * 10.0f;
  const float sa = ra * ENC_SCALE, sb = rb * ENC_SCALE;
  int pa = __builtin_amdgcn_cvt_pk_fp8_f32(a.x * sa, a.y * sa, 0, false);
  pa = __builtin_amdgcn_cvt_pk_fp8_f32(a.z * sa, a.w * sa, pa, true);
  int pb = __builtin_amdgcn_cvt_pk_fp8_f32(b.x * sb, b.y * sb, 0, false);
  pb = __builtin_amdgcn_cvt_pk_fp8_f32(b.z * sb, b.w * sb, pb, true);
  imn[(size_t)row * (D_ / 4) + t] = (unsigned int)pa;
  capn[(size_t)row * (D_ / 4) + t] = (unsigned int)pb;
}

// Kernel 2: fused fp8 tile GEMM + exp + row/col partial sums.
// 128x128 block tile, 4 waves each a 64x64 quadrant of 4x4 16x16 MFMA tiles. BK=64.
// LDS layout: [row][4 chunks of 16B], chunk stored at slot (chunk ^ ((row>>1)&3))
// -> fragment reads hit 8 distinct bank-pair groups per 16-lane phase (conflict-free).
__global__ __launch_bounds__(256) void gemm_lse_k(
    const unsigned char* __restrict__ A,   // imn fp8 [N, D]
    const unsigned char* __restrict__ B,   // capn fp8 [N, D]
    float* __restrict__ rowsum, float* __restrict__ colsum) {
  __shared__ __align__(16) unsigned char As[128 * 64];
  __shared__ __align__(16) unsigned char Bs[128 * 64];
  const int t = threadIdx.x;
  const int w = t >> 6, l = t & 63;
  const int rowBase = blockIdx.y * 128;
  const int colBase = blockIdx.x * 128;
  const int wq_m = (w >> 1) * 64, wq_n = (w & 1) * 64;

  f32x4 acc[4][4];
#pragma unroll
  for (int i = 0; i < 4; ++i)
#pragma unroll
    for (int j = 0; j < 4; ++j)
      acc[i][j] = (f32x4){0.f, 0.f, 0.f, 0.f};

  // staging: call idx covers LDS slots [idx*64, idx*64+64); lane l -> slot idx*64+l
  // slot -> row = slot>>2, slot4 = slot&3, chunk = slot4 ^ ((row>>1)&3) = (l&3)^((l>>3)&3)
  const int gcol = (((l & 3) ^ ((l >> 3) & 3)) << 4);  // byte col within 64B row chunk
  const int srow = l >> 2;                              // row within 16-row group
  const int m15 = l & 15;
  const int qh = (l >> 5) & 1, ql = (l >> 4) & 1;       // k-quarter bits
  const int swz = (m15 >> 1) & 3;

  for (int k0 = 0; k0 < D_; k0 += 64) {
#pragma unroll
    for (int j = 0; j < 4; ++j) {
      const int idx = j * 4 + w;
      load_lds16(A + (size_t)(rowBase + idx * 16 + srow) * D_ + k0 + gcol,
                 As + idx * 1024);
    }
#pragma unroll
    for (int j = 0; j < 2; ++j) {
      const int idx = j * 4 + w;
      load_lds16(B + (size_t)(colBase + idx * 16 + srow) * D_ + k0 + gcol,
                 Bs + idx * 1024);
    }
    __syncthreads();  // drain global_load_lds

#pragma unroll
    for (int s = 0; s < 2; ++s) {  // two k=32 steps within BK=64
      long af[4], bf[4];
#pragma unroll
      for (int i = 0; i < 4; ++i) {
        const int ra = wq_m + i * 16 + m15;
        af[i] = *(const long*)(As + ra * 64 + (((s * 2 + qh) ^ swz) << 4) + ql * 8);
        const int rb = wq_n + i * 16 + m15;
        bf[i] = *(const long*)(Bs + rb * 64 + (((s * 2 + qh) ^ swz) << 4) + ql * 8);
      }
#pragma unroll
      for (int mt = 0; mt < 4; ++mt)
#pragma unroll
        for (int nt = 0; nt < 4; ++nt)
          acc[mt][nt] = __builtin_amdgcn_mfma_f32_16x16x32_fp8_fp8(
              af[mt], bf[nt], acc[mt][nt], 0, 0, 0);
    }
    __syncthreads();  // protect LDS before next stage
  }

  // epilogue: exp (fixed-max LSE; |logit| <= 10, no overflow possible)
#pragma unroll
  for (int mt = 0; mt < 4; ++mt)
#pragma unroll
    for (int nt = 0; nt < 4; ++nt)
#pragma unroll
      for (int r = 0; r < 4; ++r)
        acc[mt][nt][r] = __expf(acc[mt][nt][r] * EPILOGUE_SCALE);

  // C/D layout: col = lane&15, row = (lane>>4)*4 + reg  [measured m89/m91]
#pragma unroll
  for (int mt = 0; mt < 4; ++mt)
#pragma unroll
    for (int r = 0; r < 4; ++r) {
      float v = acc[mt][0][r] + acc[mt][1][r] + acc[mt][2][r] + acc[mt][3][r];
      v += __shfl_xor(v, 1, 64);
      v += __shfl_xor(v, 2, 64);
      v += __shfl_xor(v, 4, 64);
      v += __shfl_xor(v, 8, 64);
      if ((l & 15) == 0)
        atomicAdd(&rowsum[rowBase + wq_m + mt * 16 + (l >> 4) * 4 + r], v);
    }
#pragma unroll
  for (int nt = 0; nt < 4; ++nt) {
    float v = 0.f;
#pragma unroll
    for (int mt = 0; mt < 4; ++mt)
      v += acc[mt][nt][0] + acc[mt][nt][1] + acc[mt][nt][2] + acc[mt][nt][3];
    v += __shfl_xor(v, 16, 64);
    v += __shfl_xor(v, 32, 64);
    if (l < 16)
      atomicAdd(&colsum[colBase + wq_n + nt * 16 + l], v);
  }
}

// Kernel 3: scalar reduce.
__global__ __launch_bounds__(256) void finalize_k(
    const float* __restrict__ rowsum, const float* __restrict__ colsum,
    const float* __restrict__ diag, float* __restrict__ out) {
  const int t = threadIdx.x;
  float lse = 0.f, dg = 0.f;
  for (int i = t; i < N_; i += 256) {
    lse += __logf(rowsum[i]) + __logf(colsum[i]);
    dg += diag[i];
  }
#pragma unroll
  for (int o = 32; o > 0; o >>= 1) {
    lse += __shfl_down(lse, o, 64);
    dg  += __shfl_down(dg, o, 64);
  }
  __shared__ float red[2][4];
  const int w = t >> 6, l = t & 63;
  if (l == 0) { red[0][w] = lse; red[1][w] = dg; }
  __syncthreads();
  if (t == 0) {
    lse = red[0][0] + red[0][1] + red[0][2] + red[0][3];
    dg  = red[1][0] + red[1][1] + red[1][2] + red[1][3];
    out[0] = 0.5f * lse / (float)N_ - dg / (float)N_;
  }
}

extern "C" void kernel_launch(void* const* d_in, const int* in_sizes, int n_in,
                              void* d_out, int out_size, void* d_ws, size_t ws_size,
                              hipStream_t stream) {
  const float* im = (const float*)d_in[0];
  const float* cap = (const float*)d_in[1];
  float* out = (float*)d_out;
  char* ws = (char*)d_ws;
  unsigned char* imn = (unsigned char*)ws;                 // 8 MB fp8
  unsigned char* capn = imn + (size_t)N_ * D_;             // 8 MB fp8
  float* rowsum = (float*)(ws + 2 * (size_t)N_ * D_);
  float* colsum = rowsum + N_;
  float* diag = colsum + N_;

  hipMemsetAsync(rowsum, 0, 2 * N_ * sizeof(float), stream);  // rowsum+colsum
  normalize_k<<<N_, 256, 0, stream>>>(im, cap, (unsigned int*)imn,
                                      (unsigned int*)capn, diag);
  gemm_lse_k<<<dim3(N_ / 128, N_ / 128), 256, 0, stream>>>(imn, capn, rowsum, colsum);
  finalize_k<<<1, 256, 0, stream>>>(rowsum, colsum, diag, out);
}

// Round 3
// 296.757 us; speedup vs baseline: 1.0306x; 1.0281x over previous
//
#include <hip/hip_runtime.h>
#include <stdint.h>

#define N_ 8192
#define D_ 1024
// logit = dot(imn,capn)/T; fp8 operands pre-scaled by 16 -> acc = 256*dot
#define EPILOGUE_SCALE (10.0f / 256.0f)
#define ENC_SCALE 16.0f

typedef float f32x4 __attribute__((ext_vector_type(4)));

// Swizzled fragment layout (both operands), 8 MB each:
//   frag8[s][tile][lane] (8 bytes) = fp8row[row = tile*16 + (lane&15)]
//                                        [k = (s*4 + (lane>>4))*8 .. +8]
// s in [0,32) (K=32 MFMA steps), tile in [0,512), lane in [0,64).
// A wave's fragment load for (tile, s) is 64 lanes x 8B = 512B contiguous.

// Kernel 1: row L2 norms, fp32 diag, fp8(e4m3) x16-scaled stores in fragment order.
__global__ __launch_bounds__(256) void normalize_k(
    const float* __restrict__ im, const float* __restrict__ cap,
    unsigned int* __restrict__ imn, unsigned int* __restrict__ capn,
    float* __restrict__ diag) {
  const int row = blockIdx.x;
  const int tid = threadIdx.x;
  const float4 a = ((const float4*)(im + (size_t)row * D_))[tid];
  const float4 b = ((const float4*)(cap + (size_t)row * D_))[tid];
  float ssa = a.x * a.x + a.y * a.y + a.z * a.z + a.w * a.w;
  float ssb = b.x * b.x + b.y * b.y + b.z * b.z + b.w * b.w;
  float dt  = a.x * b.x + a.y * b.y + a.z * b.z + a.w * b.w;
#pragma unroll
  for (int o = 32; o > 0; o >>= 1) {
    ssa += __shfl_down(ssa, o, 64);
    ssb += __shfl_down(ssb, o, 64);
    dt  += __shfl_down(dt, o, 64);
  }
  __shared__ float red[3][4];
  const int w = tid >> 6, l = tid & 63;
  if (l == 0) { red[0][w] = ssa; red[1][w] = ssb; red[2][w] = dt; }
  __syncthreads();
  ssa = red[0][0] + red[0][1] + red[0][2] + red[0][3];
  ssb = red[1][0] + red[1][1] + red[1][2] + red[1][3];
  dt  = red[2][0] + red[2][1] + red[2][2] + red[2][3];
  const float ra = rsqrtf(ssa), rb = rsqrtf(ssb);
  if (tid == 0) diag[row] = dt * ra * rb * 10.0f;
  const float sa = ra * ENC_SCALE, sb = rb * ENC_SCALE;
  int pa = __builtin_amdgcn_cvt_pk_fp8_f32(a.x * sa, a.y * sa, 0, false);
  pa = __builtin_amdgcn_cvt_pk_fp8_f32(a.z * sa, a.w * sa, pa, true);
  int pb = __builtin_amdgcn_cvt_pk_fp8_f32(b.x * sb, b.y * sb, 0, false);
  pb = __builtin_amdgcn_cvt_pk_fp8_f32(b.z * sb, b.w * sb, pb, true);
  // this thread holds k-bytes [4*tid, 4*tid+4) of the row -> fragment slot:
  const int til = row >> 4, m15 = row & 15;
  const int s = tid >> 3, kgl = (tid >> 1) & 3, h = tid & 1;
  const int fl = m15 | (kgl << 4);
  const unsigned idx = (unsigned)s * 65536u + (unsigned)til * 128u + fl * 2u + h;
  imn[idx] = (unsigned int)pa;
  capn[idx] = (unsigned int)pb;
}

// Kernel 2: no-LDS, no-barrier fp8 GEMM + exp + row/col partial sums.
// 128x128 block tile, 4 waves each a 64x64 quadrant of 4x4 16x16x32 MFMA tiles.
// Fragments loaded straight from the swizzled global layout (512B coalesced).
__global__ __launch_bounds__(256, 4) void gemm_lse_k(
    const unsigned char* __restrict__ A,   // swizzled imn
    const unsigned char* __restrict__ B,   // swizzled capn
    float* __restrict__ rowsum, float* __restrict__ colsum) {
  const int t = threadIdx.x;
  const int w = t >> 6, l = t & 63;
  // blockIdx.x = row panel (fast-varying -> per-XCD A-panel L2 residency),
  // blockIdx.y = col panel (8 XCDs share one B-panel at a time).
  const int rowBase = blockIdx.x * 128;
  const int colBase = blockIdx.y * 128;
  const int wq_m = (w >> 1) * 64, wq_n = (w & 1) * 64;

  // per-stream byte offsets within one s-slab (tile*512 + lane*8)
  unsigned voffA[4], voffB[4];
#pragma unroll
  for (int i = 0; i < 4; ++i) {
    voffA[i] = (unsigned)((blockIdx.x * 8 + (w >> 1) * 4 + i) * 512 + l * 8);
    voffB[i] = (unsigned)((blockIdx.y * 8 + (w & 1) * 4 + i) * 512 + l * 8);
  }

  f32x4 acc[4][4];
#pragma unroll
  for (int i = 0; i < 4; ++i)
#pragma unroll
    for (int j = 0; j < 4; ++j)
      acc[i][j] = (f32x4){0.f, 0.f, 0.f, 0.f};

  long a0[4], b0[4], a1[4], b1[4];
#pragma unroll
  for (int i = 0; i < 4; ++i) {
    a0[i] = *(const long*)(A + voffA[i]);
    b0[i] = *(const long*)(B + voffB[i]);
  }

#pragma unroll
  for (int s = 0; s < 32; s += 2) {
    {  // prefetch s+1
      const char* pA = (const char*)A + (size_t)(s + 1) * 262144;
      const char* pB = (const char*)B + (size_t)(s + 1) * 262144;
#pragma unroll
      for (int i = 0; i < 4; ++i) {
        a1[i] = *(const long*)(pA + voffA[i]);
        b1[i] = *(const long*)(pB + voffB[i]);
      }
    }
#pragma unroll
    for (int mt = 0; mt < 4; ++mt)
#pragma unroll
      for (int nt = 0; nt < 4; ++nt)
        acc[mt][nt] = __builtin_amdgcn_mfma_f32_16x16x32_fp8_fp8(
            a0[mt], b0[nt], acc[mt][nt], 0, 0, 0);
    if (s + 2 < 32) {  // prefetch s+2
      const char* pA = (const char*)A + (size_t)(s + 2) * 262144;
      const char* pB = (const char*)B + (size_t)(s + 2) * 262144;
#pragma unroll
      for (int i = 0; i < 4; ++i) {
        a0[i] = *(const long*)(pA + voffA[i]);
        b0[i] = *(const long*)(pB + voffB[i]);
      }
    }
#pragma unroll
    for (int mt = 0; mt < 4; ++mt)
#pragma unroll
      for (int nt = 0; nt < 4; ++nt)
        acc[mt][nt] = __builtin_amdgcn_mfma_f32_16x16x32_fp8_fp8(
            a1[mt], b1[nt], acc[mt][nt], 0, 0, 0);
  }

  // epilogue: exp (fixed-max LSE; |logit| <= 10, no overflow possible)
#pragma unroll
  for (int mt = 0; mt < 4; ++mt)
#pragma unroll
    for (int nt = 0; nt < 4; ++nt)
#pragma unroll
      for (int r = 0; r < 4; ++r)
        acc[mt][nt][r] = __expf(acc[mt][nt][r] * EPILOGUE_SCALE);

  // C/D layout: col = lane&15, row = (lane>>4)*4 + reg  [measured m89/m91]
#pragma unroll
  for (int mt = 0; mt < 4; ++mt)
#pragma unroll
    for (int r = 0; r < 4; ++r) {
      float v = acc[mt][0][r] + acc[mt][1][r] + acc[mt][2][r] + acc[mt][3][r];
      v += __shfl_xor(v, 1, 64);
      v += __shfl_xor(v, 2, 64);
      v += __shfl_xor(v, 4, 64);
      v += __shfl_xor(v, 8, 64);
      if ((l & 15) == 0)
        atomicAdd(&rowsum[rowBase + wq_m + mt * 16 + (l >> 4) * 4 + r], v);
    }
#pragma unroll
  for (int nt = 0; nt < 4; ++nt) {
    float v = 0.f;
#pragma unroll
    for (int mt = 0; mt < 4; ++mt)
      v += acc[mt][nt][0] + acc[mt][nt][1] + acc[mt][nt][2] + acc[mt][nt][3];
    v += __shfl_xor(v, 16, 64);
    v += __shfl_xor(v, 32, 64);
    if (l < 16)
      atomicAdd(&colsum[colBase + wq_n + nt * 16 + l], v);
  }
}

// Kernel 3: scalar reduce.
__global__ __launch_bounds__(256) void finalize_k(
    const float* __restrict__ rowsum, const float* __restrict__ colsum,
    const float* __restrict__ diag, float* __restrict__ out) {
  const int t = threadIdx.x;
  float lse = 0.f, dg = 0.f;
  for (int i = t; i < N_; i += 256) {
    lse += __logf(rowsum[i]) + __logf(colsum[i]);
    dg += diag[i];
  }
#pragma unroll
  for (int o = 32; o > 0; o >>= 1) {
    lse += __shfl_down(lse, o, 64);
    dg  += __shfl_down(dg, o, 64);
  }
  __shared__ float red[2][4];
  const int w = t >> 6, l = t & 63;
  if (l == 0) { red[0][w] = lse; red[1][w] = dg; }
  __syncthreads();
  if (t == 0) {
    lse = red[0][0] + red[0][1] + red[0][2] + red[0][3];
    dg  = red[1][0] + red[1][1] + red[1][2] + red[1][3];
    out[0] = 0.5f * lse / (float)N_ - dg / (float)N_;
  }
}

extern "C" void kernel_launch(void* const* d_in, const int* in_sizes, int n_in,
                              void* d_out, int out_size, void* d_ws, size_t ws_size,
                              hipStream_t stream) {
  const float* im = (const float*)d_in[0];
  const float* cap = (const float*)d_in[1];
  float* out = (float*)d_out;
  char* ws = (char*)d_ws;
  unsigned char* imn = (unsigned char*)ws;                 // 8 MB fp8 (swizzled)
  unsigned char* capn = imn + (size_t)N_ * D_;             // 8 MB fp8 (swizzled)
  float* rowsum = (float*)(ws + 2 * (size_t)N_ * D_);
  float* colsum = rowsum + N_;
  float* diag = colsum + N_;

  hipMemsetAsync(rowsum, 0, 2 * N_ * sizeof(float), stream);  // rowsum+colsum
  normalize_k<<<N_, 256, 0, stream>>>(im, cap, (unsigned int*)imn,
                                      (unsigned int*)capn, diag);
  gemm_lse_k<<<dim3(64, 64), 256, 0, stream>>>(imn, capn, rowsum, colsum);
  finalize_k<<<1, 256, 0, stream>>>(rowsum, colsum, diag, out);
}